// Round 1
// baseline (228.681 us; speedup 1.0000x reference)
//
#include <hip/hip_runtime.h>

#define N_LAYERS 8

// tanh(x) = 1 - 2/(exp(2x)+1), with raw-rate v_rcp_f32 (no full-precision div).
__device__ __forceinline__ float fast_tanh(float x) {
    x = fminf(15.0f, fmaxf(-15.0f, x));
    float e = __expf(2.0f * x);                       // v_mul + v_exp_f32
    float r = __builtin_amdgcn_rcpf(e + 1.0f);        // v_rcp_f32 (~1 ulp)
    return fmaf(-2.0f, r, 1.0f);
}

// One layer: z = tanh(z @ W^T + b) * s + t  (2->2)
__device__ __forceinline__ void layer2(float& z0, float& z1,
                                       float w0, float w1, float w2, float w3,
                                       float b0, float b1,
                                       float s0, float s1,
                                       float t0, float t1) {
    float a0 = fast_tanh(fmaf(z0, w0, fmaf(z1, w1, b0)));
    float a1 = fast_tanh(fmaf(z0, w2, fmaf(z1, w3, b1)));
    z0 = fmaf(a0, s0, t0);
    z1 = fmaf(a1, s1, t1);
}

__global__ __launch_bounds__(256) void fraud_kernel(
    const float* __restrict__ x, const float* __restrict__ y,
    const float* __restrict__ pW0, const float* __restrict__ pb0,
    const float* __restrict__ ps0, const float* __restrict__ pt0,
    const float* __restrict__ pWs, const float* __restrict__ pbs,
    const float* __restrict__ pss, const float* __restrict__ pts,
    const float* __restrict__ pWf, const float* __restrict__ pbf,
    float* __restrict__ out, int n4)  // n4 = N/4 (threads)
{
    int tid = blockIdx.x * blockDim.x + threadIdx.x;
    if (tid >= n4) return;

    // ---- load network parameters (wave-uniform addresses; expect s_load) ----
    float W00 = pW0[0], W01 = pW0[1], W02 = pW0[2], W03 = pW0[3];
    float B00 = pb0[0], B01 = pb0[1];
    float S00 = ps0[0], S01 = ps0[1];
    float T00 = pt0[0], T01 = pt0[1];
    float Wf0 = pWf[0], Wf1 = pWf[1], BF = pbf[0];

    float WS[N_LAYERS][4], BS[N_LAYERS][2], SS[N_LAYERS][2], TS[N_LAYERS][2];
#pragma unroll
    for (int l = 0; l < N_LAYERS; ++l) {
        WS[l][0] = pWs[l * 4 + 0]; WS[l][1] = pWs[l * 4 + 1];
        WS[l][2] = pWs[l * 4 + 2]; WS[l][3] = pWs[l * 4 + 3];
        BS[l][0] = pbs[l * 2 + 0]; BS[l][1] = pbs[l * 2 + 1];
        SS[l][0] = pss[l * 2 + 0]; SS[l][1] = pss[l * 2 + 1];
        TS[l][0] = pts[l * 2 + 0]; TS[l][1] = pts[l * 2 + 1];
    }

    // ---- load 4 pairs (2 x float4 per input; fully coalesced 16B) ----
    const float4* x4 = (const float4*)x;
    const float4* y4 = (const float4*)y;
    float4 xa = x4[2 * tid], xb = x4[2 * tid + 1];
    float4 ya = y4[2 * tid], yb = y4[2 * tid + 1];

    float zx0[4] = {xa.x, xa.z, xb.x, xb.z};
    float zx1[4] = {xa.y, xa.w, xb.y, xb.w};
    float zy0[4] = {ya.x, ya.z, yb.x, yb.z};
    float zy1[4] = {ya.y, ya.w, yb.y, yb.w};

    // ---- rbf = exp(-|x-y|^2) (gamma = 1) ----
    float r[4];
#pragma unroll
    for (int i = 0; i < 4; ++i) {
        float dx = zx0[i] - zy0[i];
        float dy = zx1[i] - zy1[i];
        r[i] = __expf(-fmaf(dx, dx, dy * dy));
    }

    // ---- input layer (both nets, 4 pairs) ----
#pragma unroll
    for (int i = 0; i < 4; ++i) {
        layer2(zx0[i], zx1[i], W00, W01, W02, W03, B00, B01, S00, S01, T00, T01);
        layer2(zy0[i], zy1[i], W00, W01, W02, W03, B00, B01, S00, S01, T00, T01);
    }

    // ---- 8 hidden layers ----
#pragma unroll
    for (int l = 0; l < N_LAYERS; ++l) {
#pragma unroll
        for (int i = 0; i < 4; ++i) {
            layer2(zx0[i], zx1[i], WS[l][0], WS[l][1], WS[l][2], WS[l][3],
                   BS[l][0], BS[l][1], SS[l][0], SS[l][1], TS[l][0], TS[l][1]);
            layer2(zy0[i], zy1[i], WS[l][0], WS[l][1], WS[l][2], WS[l][3],
                   BS[l][0], BS[l][1], SS[l][0], SS[l][1], TS[l][0], TS[l][1]);
        }
    }

    // ---- final head + combine ----
    float res[4];
#pragma unroll
    for (int i = 0; i < 4; ++i) {
        float fx = fmaf(zx0[i], Wf0, fmaf(zx1[i], Wf1, BF));
        float fy = fmaf(zy0[i], Wf0, fmaf(zy1[i], Wf1, BF));
        res[i] = r[i] * fx * fy;
    }
    ((float4*)out)[tid] = make_float4(res[0], res[1], res[2], res[3]);
}

extern "C" void kernel_launch(void* const* d_in, const int* in_sizes, int n_in,
                              void* d_out, int out_size, void* d_ws, size_t ws_size,
                              hipStream_t stream) {
    const float* x   = (const float*)d_in[0];
    const float* y   = (const float*)d_in[1];
    const float* W0  = (const float*)d_in[2];
    const float* b0  = (const float*)d_in[3];
    const float* s0  = (const float*)d_in[4];
    const float* t0  = (const float*)d_in[5];
    const float* Ws  = (const float*)d_in[6];
    const float* bs  = (const float*)d_in[7];
    const float* ss  = (const float*)d_in[8];
    const float* ts  = (const float*)d_in[9];
    const float* Wf  = (const float*)d_in[10];
    const float* bf  = (const float*)d_in[11];
    float* out = (float*)d_out;

    int n  = out_size;      // N pairs
    int n4 = n / 4;         // 4 pairs per thread (N = 2^23, divisible)
    dim3 block(256);
    dim3 grid((n4 + block.x - 1) / block.x);
    hipLaunchKernelGGL(fraud_kernel, grid, block, 0, stream,
                       x, y, W0, b0, s0, t0, Ws, bs, ss, ts, Wf, bf, out, n4);
}

// Round 2
// 228.015 us; speedup vs baseline: 1.0029x; 1.0029x over previous
//
#include <hip/hip_runtime.h>

#define N_LAYERS 8

// tanh LUT over [-9, 9]: 2048 cells, value stored at each cell CENTER.
// h = 18/2048 = 9/1024 = 0.0087890625 (exact in binary).
#define TAB_N    2048
#define TAB_H    0.0087890625f
#define TAB_INVH 113.77777777777777f   // 2048/18
#define TAB_HALFH 0.00439453125f

// tanh(x) ~= t0 + d*(1-t0^2)*(1 - d*t0); exact through 2nd order Taylor.
// abs err <= (h/2)^3 * max|tanh'''| / 6 = h^3/24 ~= 2.8e-8.
__device__ __forceinline__ float lut_tanh(const float* __restrict__ tab, float x) {
    float u = fmaf(x, TAB_INVH, 1024.0f);          // map to table coords
    u = fminf(fmaxf(u, 0.5f), 2047.499f);          // clamp (tanh saturated outside)
    int i = (int)u;                                 // trunc == floor (u >= 0)
    float fr = u - (float)i;
    float d = fmaf(fr, TAB_H, -TAB_HALFH);         // offset from cell center
    float t0 = tab[i];                              // ds_read_b32 (LDS pipe)
    float tp = fmaf(-t0, t0, 1.0f);                // 1 - t0^2
    float w  = d * tp;
    float c2 = fmaf(-d, t0, 1.0f);                 // 1 - d*t0
    return fmaf(w, c2, t0);
}

// One layer: z = tanh(z @ W^T + b) * s + t  (2->2)
__device__ __forceinline__ void layer2(const float* __restrict__ tab,
                                       float& z0, float& z1,
                                       float w0, float w1, float w2, float w3,
                                       float b0, float b1,
                                       float s0, float s1,
                                       float t0, float t1) {
    float a0 = lut_tanh(tab, fmaf(z0, w0, fmaf(z1, w1, b0)));
    float a1 = lut_tanh(tab, fmaf(z0, w2, fmaf(z1, w3, b1)));
    z0 = fmaf(a0, s0, t0);
    z1 = fmaf(a1, s1, t1);
}

__global__ __launch_bounds__(256) void fraud_kernel(
    const float* __restrict__ x, const float* __restrict__ y,
    const float* __restrict__ pW0, const float* __restrict__ pb0,
    const float* __restrict__ ps0, const float* __restrict__ pt0,
    const float* __restrict__ pWs, const float* __restrict__ pbs,
    const float* __restrict__ pss, const float* __restrict__ pts,
    const float* __restrict__ pWf, const float* __restrict__ pbf,
    float* __restrict__ out, int n4)  // n4 = N/4 (threads)
{
    __shared__ float tab[TAB_N];
    // Build tanh table once per block: 2048 entries / 256 threads = 8 each.
    for (int j = threadIdx.x; j < TAB_N; j += 256)
        tab[j] = tanhf(fmaf((float)j + 0.5f, TAB_H, -9.0f));
    __syncthreads();

    int tid = blockIdx.x * blockDim.x + threadIdx.x;
    if (tid >= n4) return;

    // ---- network parameters (wave-uniform; compiler scalarizes to s_load) ----
    float W00 = pW0[0], W01 = pW0[1], W02 = pW0[2], W03 = pW0[3];
    float B00 = pb0[0], B01 = pb0[1];
    float S00 = ps0[0], S01 = ps0[1];
    float T00 = pt0[0], T01 = pt0[1];
    float Wf0 = pWf[0], Wf1 = pWf[1], BF = pbf[0];

    float WS[N_LAYERS][4], BS[N_LAYERS][2], SS[N_LAYERS][2], TS[N_LAYERS][2];
#pragma unroll
    for (int l = 0; l < N_LAYERS; ++l) {
        WS[l][0] = pWs[l * 4 + 0]; WS[l][1] = pWs[l * 4 + 1];
        WS[l][2] = pWs[l * 4 + 2]; WS[l][3] = pWs[l * 4 + 3];
        BS[l][0] = pbs[l * 2 + 0]; BS[l][1] = pbs[l * 2 + 1];
        SS[l][0] = pss[l * 2 + 0]; SS[l][1] = pss[l * 2 + 1];
        TS[l][0] = pts[l * 2 + 0]; TS[l][1] = pts[l * 2 + 1];
    }

    // ---- load 4 pairs (2 x float4 per input; fully coalesced 16B) ----
    const float4* x4 = (const float4*)x;
    const float4* y4 = (const float4*)y;
    float4 xa = x4[2 * tid], xb = x4[2 * tid + 1];
    float4 ya = y4[2 * tid], yb = y4[2 * tid + 1];

    float zx0[4] = {xa.x, xa.z, xb.x, xb.z};
    float zx1[4] = {xa.y, xa.w, xb.y, xb.w};
    float zy0[4] = {ya.x, ya.z, yb.x, yb.z};
    float zy1[4] = {ya.y, ya.w, yb.y, yb.w};

    // ---- rbf = exp(-|x-y|^2) (gamma = 1); only remaining trans ops ----
    float r[4];
#pragma unroll
    for (int i = 0; i < 4; ++i) {
        float dx = zx0[i] - zy0[i];
        float dy = zx1[i] - zy1[i];
        r[i] = __expf(-fmaf(dx, dx, dy * dy));
    }

    // ---- input layer (both nets, 4 pairs) ----
#pragma unroll
    for (int i = 0; i < 4; ++i) {
        layer2(tab, zx0[i], zx1[i], W00, W01, W02, W03, B00, B01, S00, S01, T00, T01);
        layer2(tab, zy0[i], zy1[i], W00, W01, W02, W03, B00, B01, S00, S01, T00, T01);
    }

    // ---- 8 hidden layers ----
#pragma unroll
    for (int l = 0; l < N_LAYERS; ++l) {
#pragma unroll
        for (int i = 0; i < 4; ++i) {
            layer2(tab, zx0[i], zx1[i], WS[l][0], WS[l][1], WS[l][2], WS[l][3],
                   BS[l][0], BS[l][1], SS[l][0], SS[l][1], TS[l][0], TS[l][1]);
            layer2(tab, zy0[i], zy1[i], WS[l][0], WS[l][1], WS[l][2], WS[l][3],
                   BS[l][0], BS[l][1], SS[l][0], SS[l][1], TS[l][0], TS[l][1]);
        }
    }

    // ---- final head + combine ----
    float res[4];
#pragma unroll
    for (int i = 0; i < 4; ++i) {
        float fx = fmaf(zx0[i], Wf0, fmaf(zx1[i], Wf1, BF));
        float fy = fmaf(zy0[i], Wf0, fmaf(zy1[i], Wf1, BF));
        res[i] = r[i] * fx * fy;
    }
    ((float4*)out)[tid] = make_float4(res[0], res[1], res[2], res[3]);
}

extern "C" void kernel_launch(void* const* d_in, const int* in_sizes, int n_in,
                              void* d_out, int out_size, void* d_ws, size_t ws_size,
                              hipStream_t stream) {
    const float* x   = (const float*)d_in[0];
    const float* y   = (const float*)d_in[1];
    const float* W0  = (const float*)d_in[2];
    const float* b0  = (const float*)d_in[3];
    const float* s0  = (const float*)d_in[4];
    const float* t0  = (const float*)d_in[5];
    const float* Ws  = (const float*)d_in[6];
    const float* bs  = (const float*)d_in[7];
    const float* ss  = (const float*)d_in[8];
    const float* ts  = (const float*)d_in[9];
    const float* Wf  = (const float*)d_in[10];
    const float* bf  = (const float*)d_in[11];
    float* out = (float*)d_out;

    int n  = out_size;      // N pairs
    int n4 = n / 4;         // 4 pairs per thread (N = 2^23, divisible)
    dim3 block(256);
    dim3 grid((n4 + block.x - 1) / block.x);
    hipLaunchKernelGGL(fraud_kernel, grid, block, 0, stream,
                       x, y, W0, b0, s0, t0, Ws, bs, ss, ts, Wf, bf, out, n4);
}

// Round 3
// 211.718 us; speedup vs baseline: 1.0801x; 1.0770x over previous
//
#include <hip/hip_runtime.h>

#define N_LAYERS 8
#define LOG2E2 2.8853900817779268f   // 2*log2(e)
#define NLOG2E 1.4426950408889634f   // log2(e)

#if __has_builtin(__builtin_amdgcn_exp2f)
__device__ __forceinline__ float exp2_fast(float x) { return __builtin_amdgcn_exp2f(x); }
#else
__device__ __forceinline__ float exp2_fast(float x) { return __expf(0.6931471805599453f * x); }
#endif

// ---- setup: fold scale/shift + 2log2e into per-layer weights, into d_ws ----
// fp layout: [0..5]   layer0: W~(4), b~(2)          (log2-domain)
//            [6+6l .. ] hidden l: W~(4), b~(2)      (log2-domain, prev s/t folded)
//            [54..56] head: W~f(2), b~f(1)          (natural domain, s8/t8 folded)
__global__ void fold_params(const float* __restrict__ W0, const float* __restrict__ b0,
                            const float* __restrict__ s0, const float* __restrict__ t0,
                            const float* __restrict__ Ws, const float* __restrict__ bs,
                            const float* __restrict__ ss, const float* __restrict__ ts,
                            const float* __restrict__ Wf, const float* __restrict__ bf,
                            float* __restrict__ fp) {
    if (threadIdx.x == 0 && blockIdx.x == 0) {
        fp[0] = LOG2E2 * W0[0]; fp[1] = LOG2E2 * W0[1];
        fp[2] = LOG2E2 * W0[2]; fp[3] = LOG2E2 * W0[3];
        fp[4] = LOG2E2 * b0[0]; fp[5] = LOG2E2 * b0[1];
        for (int l = 0; l < N_LAYERS; ++l) {
            float ps0 = (l == 0) ? s0[0] : ss[(l - 1) * 2 + 0];
            float ps1 = (l == 0) ? s0[1] : ss[(l - 1) * 2 + 1];
            float pt0 = (l == 0) ? t0[0] : ts[(l - 1) * 2 + 0];
            float pt1 = (l == 0) ? t0[1] : ts[(l - 1) * 2 + 1];
            const float* W = Ws + l * 4;
            const float* b = bs + l * 2;
            float* o = fp + 6 + l * 6;
            o[0] = LOG2E2 * W[0] * ps0; o[1] = LOG2E2 * W[1] * ps1;
            o[2] = LOG2E2 * W[2] * ps0; o[3] = LOG2E2 * W[3] * ps1;
            o[4] = LOG2E2 * (W[0] * pt0 + W[1] * pt1 + b[0]);
            o[5] = LOG2E2 * (W[2] * pt0 + W[3] * pt1 + b[1]);
        }
        fp[54] = Wf[0] * ss[14];
        fp[55] = Wf[1] * ss[15];
        fp[56] = Wf[0] * ts[14] + Wf[1] * ts[15] + bf[0];
    }
}

// tanh from log2-domain preactivation u (= 2*log2e*x): t = 1 - 2/(2^u + 1).
// 4 at once with Montgomery batched reciprocal: 1 v_rcp + 9 mul for 4 inverses.
// u clamped at 30 so product of 4 denominators <= 2^120 (clamp err ~9e-10).
__device__ __forceinline__ void tanh4_log2(const float u[4], float t[4]) {
    float d[4];
#pragma unroll
    for (int i = 0; i < 4; ++i)
        d[i] = exp2_fast(fminf(u[i], 30.0f)) + 1.0f;
    float p2 = d[0] * d[1];
    float p3 = p2 * d[2];
    float p4 = p3 * d[3];
    float R = __builtin_amdgcn_rcpf(p4);
    float i3 = R * p3;  R *= d[3];        // 1/d3 ; R = 1/p3
    float i2 = R * p2;  R *= d[2];        // 1/d2 ; R = 1/(d0 d1)
    float i1 = R * d[0];                  // 1/d1
    float i0 = R * d[1];                  // 1/d0
    t[0] = fmaf(-2.0f, i0, 1.0f);
    t[1] = fmaf(-2.0f, i1, 1.0f);
    t[2] = fmaf(-2.0f, i2, 1.0f);
    t[3] = fmaf(-2.0f, i3, 1.0f);
}

// One folded layer for 4 pairs of one net: a <- tanh_log2(W~ a + b~)
__device__ __forceinline__ void layer4(const float* __restrict__ o,
                                       float a0[4], float a1[4]) {
    float w0 = o[0], w1 = o[1], w2 = o[2], w3 = o[3], c0 = o[4], c1 = o[5];
    float u0[4], u1[4];
#pragma unroll
    for (int i = 0; i < 4; ++i) {
        u0[i] = fmaf(a0[i], w0, fmaf(a1[i], w1, c0));
        u1[i] = fmaf(a0[i], w2, fmaf(a1[i], w3, c1));
    }
    tanh4_log2(u0, a0);
    tanh4_log2(u1, a1);
}

__global__ __launch_bounds__(256) void fraud_kernel(
    const float* __restrict__ x, const float* __restrict__ y,
    const float* __restrict__ fp,
    float* __restrict__ out, int n4)  // n4 = N/4 threads
{
    int tid = blockIdx.x * blockDim.x + threadIdx.x;
    if (tid >= n4) return;

    // ---- load 4 pairs (2 x float4 per input; coalesced 16B) ----
    const float4* x4 = (const float4*)x;
    const float4* y4 = (const float4*)y;
    float4 xa = x4[2 * tid], xb = x4[2 * tid + 1];
    float4 ya = y4[2 * tid], yb = y4[2 * tid + 1];

    float zx0[4] = {xa.x, xa.z, xb.x, xb.z};
    float zx1[4] = {xa.y, xa.w, xb.y, xb.w};
    float zy0[4] = {ya.x, ya.z, yb.x, yb.z};
    float zy1[4] = {ya.y, ya.w, yb.y, yb.w};

    // ---- rbf = 2^(-log2e * |x-y|^2) ----
    float r[4];
#pragma unroll
    for (int i = 0; i < 4; ++i) {
        float dx = zx0[i] - zy0[i];
        float dy = zx1[i] - zy1[i];
        r[i] = exp2_fast(-NLOG2E * fmaf(dx, dx, dy * dy));
    }

    // ---- both nets: 9 folded layers each (all params via s_load, uniform) ----
#pragma unroll
    for (int l = 0; l <= N_LAYERS; ++l) {
        const float* o = fp + l * 6;   // l=0 is input layer, 1..8 hidden
        layer4(o, zx0, zx1);
        layer4(o, zy0, zy1);
    }

    // ---- folded head + combine ----
    float wf0 = fp[54], wf1 = fp[55], bf_ = fp[56];
    float res[4];
#pragma unroll
    for (int i = 0; i < 4; ++i) {
        float fx = fmaf(zx0[i], wf0, fmaf(zx1[i], wf1, bf_));
        float fy = fmaf(zy0[i], wf0, fmaf(zy1[i], wf1, bf_));
        res[i] = r[i] * fx * fy;
    }
    ((float4*)out)[tid] = make_float4(res[0], res[1], res[2], res[3]);
}

extern "C" void kernel_launch(void* const* d_in, const int* in_sizes, int n_in,
                              void* d_out, int out_size, void* d_ws, size_t ws_size,
                              hipStream_t stream) {
    const float* x  = (const float*)d_in[0];
    const float* y  = (const float*)d_in[1];
    const float* W0 = (const float*)d_in[2];
    const float* b0 = (const float*)d_in[3];
    const float* s0 = (const float*)d_in[4];
    const float* t0 = (const float*)d_in[5];
    const float* Ws = (const float*)d_in[6];
    const float* bs = (const float*)d_in[7];
    const float* ss = (const float*)d_in[8];
    const float* ts = (const float*)d_in[9];
    const float* Wf = (const float*)d_in[10];
    const float* bf = (const float*)d_in[11];
    float* out = (float*)d_out;
    float* fp  = (float*)d_ws;   // 57 floats of folded params

    hipLaunchKernelGGL(fold_params, dim3(1), dim3(64), 0, stream,
                       W0, b0, s0, t0, Ws, bs, ss, ts, Wf, bf, fp);

    int n  = out_size;
    int n4 = n / 4;
    dim3 block(256);
    dim3 grid((n4 + block.x - 1) / block.x);
    hipLaunchKernelGGL(fraud_kernel, grid, block, 0, stream,
                       x, y, fp, out, n4);
}

// Round 4
// 199.750 us; speedup vs baseline: 1.1448x; 1.0599x over previous
//
#include <hip/hip_runtime.h>
#include <math.h>

#define N_LAYERS 8
#define TAB 64
#define TABSZ (TAB * TAB)
#define LOG2E2 2.8853900817779268f   // 2*log2(e)
#define NLOG2E 1.4426950408889634f   // log2(e)
#define UCLAMP 24.0f                  // exp2 clamp: 4-product <= 2^96, tanh err 1.2e-7

#if __has_builtin(__builtin_amdgcn_exp2f)
__device__ __forceinline__ float exp2_fast(float x) { return __builtin_amdgcn_exp2f(x); }
#else
__device__ __forceinline__ float exp2_fast(float x) { return __expf(0.6931471805599453f * x); }
#endif

// d_ws float layout:
//  [0..3]  Wt  = LOG2E2 * W0      (log2-domain input-layer weights)
//  [4..5]  bt  = LOG2E2 * b0
//  [6..7]  C   (u = C - D*i  table-coord map, i = 1/(2^p+1))
//  [8..9]  D
//  [10..11] lo  (table domain lower corner)
//  [12..13] h   (table cell size)
//  [16 ..]  table g(a0,a1), TABSZ floats
__global__ void setup_meta(const float* __restrict__ W0, const float* __restrict__ b0,
                           const float* __restrict__ s0, const float* __restrict__ t0,
                           float* __restrict__ fp) {
    if (threadIdx.x == 0 && blockIdx.x == 0) {
        fp[0] = LOG2E2 * W0[0]; fp[1] = LOG2E2 * W0[1];
        fp[2] = LOG2E2 * W0[2]; fp[3] = LOG2E2 * W0[3];
        fp[4] = LOG2E2 * b0[0]; fp[5] = LOG2E2 * b0[1];
        for (int c = 0; c < 2; ++c) {
            float s = s0[c], t = t0[c];
            float span = fmaxf(2.2f * s, 1e-5f);   // 10% pad each side for CR stencil
            float h  = span / (float)(TAB - 1);
            float lo = t - 0.5f * span;
            float ih = (float)(TAB - 1) / span;
            // a = t + s - 2*s*i  ->  u = (a - lo)/h = C - D*i
            fp[6 + c]  = (s + 0.5f * span) * ih;   // C
            fp[8 + c]  = 2.0f * s * ih;            // D
            fp[10 + c] = lo;
            fp[12 + c] = h;
        }
    }
}

// Evaluate layers 1..8 + head exactly on the grid (one-time, precise tanhf).
__global__ void build_table(const float* __restrict__ Ws, const float* __restrict__ bs,
                            const float* __restrict__ ss, const float* __restrict__ ts,
                            const float* __restrict__ Wf, const float* __restrict__ bf,
                            const float* __restrict__ fp, float* __restrict__ gt) {
    int idx = blockIdx.x * 256 + threadIdx.x;
    if (idx >= TABSZ) return;
    int k0 = idx & (TAB - 1);
    int k1 = idx >> 6;
    float z0 = fp[10] + (float)k0 * fp[12];
    float z1 = fp[11] + (float)k1 * fp[13];
    for (int l = 0; l < N_LAYERS; ++l) {
        float u0 = fmaf(z0, Ws[4 * l + 0], fmaf(z1, Ws[4 * l + 1], bs[2 * l + 0]));
        float u1 = fmaf(z0, Ws[4 * l + 2], fmaf(z1, Ws[4 * l + 3], bs[2 * l + 1]));
        z0 = fmaf(tanhf(u0), ss[2 * l + 0], ts[2 * l + 0]);
        z1 = fmaf(tanhf(u1), ss[2 * l + 1], ts[2 * l + 1]);
    }
    gt[idx] = fmaf(z0, Wf[0], fmaf(z1, Wf[1], bf[0]));
}

// Catmull-Rom weights (exact for cubics, C1).
__device__ __forceinline__ void cr_w(float f, float w[4]) {
    w[0] = f * fmaf(f, fmaf(f, -0.5f, 1.0f), -0.5f);
    w[1] = fmaf(f * f, fmaf(f, 1.5f, -2.5f), 1.0f);
    w[2] = f * fmaf(f, fmaf(f, -1.5f, 2.0f), 0.5f);
    w[3] = f * f * fmaf(f, 0.5f, -0.5f);
}

__device__ __forceinline__ float interp2d(const float* __restrict__ tab, float u0, float u1) {
    int ix = (int)u0, iy = (int)u1;
    ix = min(max(ix, 1), TAB - 3);
    iy = min(max(iy, 1), TAB - 3);
    float fx = u0 - (float)ix, fy = u1 - (float)iy;
    float wx[4], wy[4];
    cr_w(fx, wx);
    cr_w(fy, wy);
    const float* p = tab + (iy - 1) * TAB + (ix - 1);
    float r0 = fmaf(p[3], wx[3], fmaf(p[2], wx[2], fmaf(p[1], wx[1], p[0] * wx[0]))); p += TAB;
    float r1 = fmaf(p[3], wx[3], fmaf(p[2], wx[2], fmaf(p[1], wx[1], p[0] * wx[0]))); p += TAB;
    float r2 = fmaf(p[3], wx[3], fmaf(p[2], wx[2], fmaf(p[1], wx[1], p[0] * wx[0]))); p += TAB;
    float r3 = fmaf(p[3], wx[3], fmaf(p[2], wx[2], fmaf(p[1], wx[1], p[0] * wx[0])));
    return fmaf(r3, wy[3], fmaf(r2, wy[2], fmaf(r1, wy[1], r0 * wy[0])));
}

// One pair: exact input layer via exp2 + Montgomery-4 reciprocal, then 2 table lookups.
__device__ __forceinline__ float pair_val(const float* __restrict__ tab,
                                          float px0, float px1, float py0, float py1,
                                          float C0, float C1, float D0, float D1) {
    float d0 = exp2_fast(fminf(px0, UCLAMP)) + 1.0f;
    float d1 = exp2_fast(fminf(px1, UCLAMP)) + 1.0f;
    float d2 = exp2_fast(fminf(py0, UCLAMP)) + 1.0f;
    float d3 = exp2_fast(fminf(py1, UCLAMP)) + 1.0f;
    float p2 = d0 * d1, p3 = p2 * d2, p4 = p3 * d3;
    float R = __builtin_amdgcn_rcpf(p4);
    float i3 = R * p3;  R *= d3;
    float i2 = R * p2;  R *= d2;
    float i1 = R * d0;
    float i0 = R * d1;
    float ux0 = fmaf(-D0, i0, C0), ux1 = fmaf(-D1, i1, C1);
    float uy0 = fmaf(-D0, i2, C0), uy1 = fmaf(-D1, i3, C1);
    return interp2d(tab, ux0, ux1) * interp2d(tab, uy0, uy1);
}

__global__ __launch_bounds__(256, 4) void fraud_kernel(
    const float4* __restrict__ x4, const float4* __restrict__ y4,
    const float* __restrict__ fp, const float* __restrict__ gt,
    float2* __restrict__ out2, int stride)   // stride = total threads; 4 groups/thread
{
    __shared__ float tab[TABSZ];
    {   // stage 16 KB table: 1024 float4s / 256 threads = 4 each
        const float4* g4 = (const float4*)gt;
        float4* t4 = (float4*)tab;
        for (int j = threadIdx.x; j < TABSZ / 4; j += 256) t4[j] = g4[j];
    }
    __syncthreads();

    float Wt0 = fp[0], Wt1 = fp[1], Wt2 = fp[2], Wt3 = fp[3];
    float bt0 = fp[4], bt1 = fp[5];
    float C0 = fp[6], C1 = fp[7], D0 = fp[8], D1 = fp[9];

    int tid = blockIdx.x * 256 + threadIdx.x;
#pragma unroll
    for (int k = 0; k < 4; ++k) {
        int g = tid + k * stride;        // coalesced float4 per lane
        float4 xa = x4[g], ya = y4[g];   // 2 pairs: (x,y) and (z,w)

        // pair A
        float pxa0 = fmaf(xa.x, Wt0, fmaf(xa.y, Wt1, bt0));
        float pxa1 = fmaf(xa.x, Wt2, fmaf(xa.y, Wt3, bt1));
        float pya0 = fmaf(ya.x, Wt0, fmaf(ya.y, Wt1, bt0));
        float pya1 = fmaf(ya.x, Wt2, fmaf(ya.y, Wt3, bt1));
        float dxA = xa.x - ya.x, dyA = xa.y - ya.y;
        float rA = exp2_fast(-NLOG2E * fmaf(dxA, dxA, dyA * dyA));
        float resA = rA * pair_val(tab, pxa0, pxa1, pya0, pya1, C0, C1, D0, D1);

        // pair B
        float pxb0 = fmaf(xa.z, Wt0, fmaf(xa.w, Wt1, bt0));
        float pxb1 = fmaf(xa.z, Wt2, fmaf(xa.w, Wt3, bt1));
        float pyb0 = fmaf(ya.z, Wt0, fmaf(ya.w, Wt1, bt0));
        float pyb1 = fmaf(ya.z, Wt2, fmaf(ya.w, Wt3, bt1));
        float dxB = xa.z - ya.z, dyB = xa.w - ya.w;
        float rB = exp2_fast(-NLOG2E * fmaf(dxB, dxB, dyB * dyB));
        float resB = rB * pair_val(tab, pxb0, pxb1, pyb0, pyb1, C0, C1, D0, D1);

        out2[g] = make_float2(resA, resB);
    }
}

extern "C" void kernel_launch(void* const* d_in, const int* in_sizes, int n_in,
                              void* d_out, int out_size, void* d_ws, size_t ws_size,
                              hipStream_t stream) {
    const float* x  = (const float*)d_in[0];
    const float* y  = (const float*)d_in[1];
    const float* W0 = (const float*)d_in[2];
    const float* b0 = (const float*)d_in[3];
    const float* s0 = (const float*)d_in[4];
    const float* t0 = (const float*)d_in[5];
    const float* Ws = (const float*)d_in[6];
    const float* bs = (const float*)d_in[7];
    const float* ss = (const float*)d_in[8];
    const float* ts = (const float*)d_in[9];
    const float* Wf = (const float*)d_in[10];
    const float* bf = (const float*)d_in[11];
    float* out = (float*)d_out;
    float* fp  = (float*)d_ws;
    float* gt  = fp + 16;

    hipLaunchKernelGGL(setup_meta, dim3(1), dim3(64), 0, stream, W0, b0, s0, t0, fp);
    hipLaunchKernelGGL(build_table, dim3(TABSZ / 256), dim3(256), 0, stream,
                       Ws, bs, ss, ts, Wf, bf, fp, gt);

    int n       = out_size;          // 8,388,608 pairs
    int ngroups = n / 2;             // float4-groups of 2 pairs
    int threads = ngroups / 4;       // 4 groups per thread = 8 pairs
    dim3 block(256);
    dim3 grid(threads / 256);
    hipLaunchKernelGGL(fraud_kernel, grid, block, 0, stream,
                       (const float4*)x, (const float4*)y, fp, gt,
                       (float2*)out, threads);
}

// Round 5
// 193.926 us; speedup vs baseline: 1.1792x; 1.0300x over previous
//
#include <hip/hip_runtime.h>
#include <math.h>

#define N_LAYERS 8
#define TAB 48
#define TABSZ (TAB * TAB)
#define LOG2E2 2.8853900817779268f   // 2*log2(e)
#define NLOG2E 1.4426950408889634f   // log2(e)
#define UCLAMP 24.0f                  // exp2 clamp: 4-product <= 2^96

#if __has_builtin(__builtin_amdgcn_exp2f)
__device__ __forceinline__ float exp2_fast(float x) { return __builtin_amdgcn_exp2f(x); }
#else
__device__ __forceinline__ float exp2_fast(float x) { return __expf(0.6931471805599453f * x); }
#endif

// d_ws float layout:
//  [0..5]   log2-domain input layer (W~ 4, b~ 2)
//  [6..9]   C0,C1,D0,D1   (u = C - D*i table-coord map)
//  [10..13] lo0,lo1,h0,h1 (table domain)
//  [16 ..]              gt   : unpacked g table, TABSZ floats
//  [16+TABSZ ..]        gt4  : packed CR rows, TABSZ float4 (16B aligned)
__global__ void setup_meta(const float* __restrict__ W0, const float* __restrict__ b0,
                           const float* __restrict__ s0, const float* __restrict__ t0,
                           float* __restrict__ fp) {
    if (threadIdx.x == 0 && blockIdx.x == 0) {
        fp[0] = LOG2E2 * W0[0]; fp[1] = LOG2E2 * W0[1];
        fp[2] = LOG2E2 * W0[2]; fp[3] = LOG2E2 * W0[3];
        fp[4] = LOG2E2 * b0[0]; fp[5] = LOG2E2 * b0[1];
        for (int c = 0; c < 2; ++c) {
            float s = s0[c], t = t0[c];
            float span = fmaxf(2.2f * s, 1e-5f);   // 10% pad each side; u lands in [2.1,44.9]
            float h  = span / (float)(TAB - 1);
            float lo = t - 0.5f * span;
            float ih = (float)(TAB - 1) / span;
            fp[6 + c]  = (s + 0.5f * span) * ih;   // C
            fp[8 + c]  = 2.0f * s * ih;            // D
            fp[10 + c] = lo;
            fp[12 + c] = h;
        }
    }
}

// Exact evaluation of layers 1..8 + head on the grid (one-time, tanhf).
__global__ void build_table(const float* __restrict__ Ws, const float* __restrict__ bs,
                            const float* __restrict__ ss, const float* __restrict__ ts,
                            const float* __restrict__ Wf, const float* __restrict__ bf,
                            const float* __restrict__ fp, float* __restrict__ gt) {
    int idx = blockIdx.x * 256 + threadIdx.x;
    if (idx >= TABSZ) return;
    int k1 = idx / TAB, k0 = idx - k1 * TAB;
    float z0 = fp[10] + (float)k0 * fp[12];
    float z1 = fp[11] + (float)k1 * fp[13];
    for (int l = 0; l < N_LAYERS; ++l) {
        float u0 = fmaf(z0, Ws[4 * l + 0], fmaf(z1, Ws[4 * l + 1], bs[2 * l + 0]));
        float u1 = fmaf(z0, Ws[4 * l + 2], fmaf(z1, Ws[4 * l + 3], bs[2 * l + 1]));
        z0 = fmaf(tanhf(u0), ss[2 * l + 0], ts[2 * l + 0]);
        z1 = fmaf(tanhf(u1), ss[2 * l + 1], ts[2 * l + 1]);
    }
    gt[idx] = fmaf(z0, Wf[0], fmaf(z1, Wf[1], bf[0]));
}

// Pack Catmull-Rom row taps: gt4[iy*TAB+ix] = g[iy][ix-1..ix+2] (cols clamped).
__global__ void pack_table(const float* __restrict__ gt, float4* __restrict__ gt4) {
    int idx = blockIdx.x * 256 + threadIdx.x;
    if (idx >= TABSZ) return;
    int iy = idx / TAB, ix = idx - iy * TAB;
    const float* row = gt + iy * TAB;
    int c0 = max(ix - 1, 0);
    int c1 = ix;
    int c2 = min(ix + 1, TAB - 1);
    int c3 = min(ix + 2, TAB - 1);
    gt4[idx] = make_float4(row[c0], row[c1], row[c2], row[c3]);
}

// Catmull-Rom weights.
__device__ __forceinline__ void cr_w(float f, float w[4]) {
    w[0] = f * fmaf(f, fmaf(f, -0.5f, 1.0f), -0.5f);
    w[1] = fmaf(f * f, fmaf(f, 1.5f, -2.5f), 1.0f);
    w[2] = f * fmaf(f, fmaf(f, -1.5f, 2.0f), 0.5f);
    w[3] = f * f * fmaf(f, 0.5f, -0.5f);
}

// Both nets' table lookups fused: 8 ds_read_b128 outstanding together.
__device__ __forceinline__ float interp_two(const float4* __restrict__ tab4,
                                            float ax0, float ax1, float ay0, float ay1) {
    int ixa = min(max((int)ax0, 1), TAB - 3);
    int iya = min(max((int)ax1, 1), TAB - 3);
    int ixb = min(max((int)ay0, 1), TAB - 3);
    int iyb = min(max((int)ay1, 1), TAB - 3);
    float fxa = ax0 - (float)ixa, fya = ax1 - (float)iya;
    float fxb = ay0 - (float)ixb, fyb = ay1 - (float)iyb;

    const float4* pa = tab4 + (iya - 1) * TAB + ixa;
    const float4* pb = tab4 + (iyb - 1) * TAB + ixb;
    float4 a0 = pa[0], a1 = pa[TAB], a2 = pa[2 * TAB], a3 = pa[3 * TAB];
    float4 b0 = pb[0], b1 = pb[TAB], b2 = pb[2 * TAB], b3 = pb[3 * TAB];

    float wxa[4], wya[4], wxb[4], wyb[4];
    cr_w(fxa, wxa); cr_w(fya, wya);
    cr_w(fxb, wxb); cr_w(fyb, wyb);

    float ra0 = fmaf(a0.w, wxa[3], fmaf(a0.z, wxa[2], fmaf(a0.y, wxa[1], a0.x * wxa[0])));
    float ra1 = fmaf(a1.w, wxa[3], fmaf(a1.z, wxa[2], fmaf(a1.y, wxa[1], a1.x * wxa[0])));
    float ra2 = fmaf(a2.w, wxa[3], fmaf(a2.z, wxa[2], fmaf(a2.y, wxa[1], a2.x * wxa[0])));
    float ra3 = fmaf(a3.w, wxa[3], fmaf(a3.z, wxa[2], fmaf(a3.y, wxa[1], a3.x * wxa[0])));
    float gx  = fmaf(ra3, wya[3], fmaf(ra2, wya[2], fmaf(ra1, wya[1], ra0 * wya[0])));

    float rb0 = fmaf(b0.w, wxb[3], fmaf(b0.z, wxb[2], fmaf(b0.y, wxb[1], b0.x * wxb[0])));
    float rb1 = fmaf(b1.w, wxb[3], fmaf(b1.z, wxb[2], fmaf(b1.y, wxb[1], b1.x * wxb[0])));
    float rb2 = fmaf(b2.w, wxb[3], fmaf(b2.z, wxb[2], fmaf(b2.y, wxb[1], b2.x * wxb[0])));
    float rb3 = fmaf(b3.w, wxb[3], fmaf(b3.z, wxb[2], fmaf(b3.y, wxb[1], b3.x * wxb[0])));
    float gy  = fmaf(rb3, wyb[3], fmaf(rb2, wyb[2], fmaf(rb1, wyb[1], rb0 * wyb[0])));

    return gx * gy;
}

// One pair: exact log2-domain input layer + Montgomery-4 rcp, then fused lookups.
__device__ __forceinline__ float pair_val(const float4* __restrict__ tab4,
                                          float px0, float px1, float py0, float py1,
                                          float C0, float C1, float D0, float D1) {
    float d0 = exp2_fast(fminf(px0, UCLAMP)) + 1.0f;
    float d1 = exp2_fast(fminf(px1, UCLAMP)) + 1.0f;
    float d2 = exp2_fast(fminf(py0, UCLAMP)) + 1.0f;
    float d3 = exp2_fast(fminf(py1, UCLAMP)) + 1.0f;
    float p2 = d0 * d1, p3 = p2 * d2, p4 = p3 * d3;
    float R = __builtin_amdgcn_rcpf(p4);
    float i3 = R * p3;  R *= d3;
    float i2 = R * p2;  R *= d2;
    float i1 = R * d0;
    float i0 = R * d1;
    float ux0 = fmaf(-D0, i0, C0), ux1 = fmaf(-D1, i1, C1);
    float uy0 = fmaf(-D0, i2, C0), uy1 = fmaf(-D1, i3, C1);
    return interp_two(tab4, ux0, ux1, uy0, uy1);
}

__global__ __launch_bounds__(256) void fraud_kernel(
    const float4* __restrict__ x4, const float4* __restrict__ y4,
    const float* __restrict__ fp, const float4* __restrict__ gt4,
    float2* __restrict__ out2, int stride)   // 4 float4-groups (8 pairs) per thread
{
    __shared__ float4 tab4[TABSZ];   // 36 KB packed CR rows
    for (int j = threadIdx.x; j < TABSZ; j += 256) tab4[j] = gt4[j];
    __syncthreads();

    float Wt0 = fp[0], Wt1 = fp[1], Wt2 = fp[2], Wt3 = fp[3];
    float bt0 = fp[4], bt1 = fp[5];
    float C0 = fp[6], C1 = fp[7], D0 = fp[8], D1 = fp[9];

    int tid = blockIdx.x * 256 + threadIdx.x;
#pragma unroll
    for (int k = 0; k < 4; ++k) {
        int g = tid + k * stride;        // coalesced float4 per lane
        float4 xa = x4[g], ya = y4[g];   // 2 pairs

        float pxa0 = fmaf(xa.x, Wt0, fmaf(xa.y, Wt1, bt0));
        float pxa1 = fmaf(xa.x, Wt2, fmaf(xa.y, Wt3, bt1));
        float pya0 = fmaf(ya.x, Wt0, fmaf(ya.y, Wt1, bt0));
        float pya1 = fmaf(ya.x, Wt2, fmaf(ya.y, Wt3, bt1));
        float dxA = xa.x - ya.x, dyA = xa.y - ya.y;
        float rA = exp2_fast(-NLOG2E * fmaf(dxA, dxA, dyA * dyA));
        float resA = rA * pair_val(tab4, pxa0, pxa1, pya0, pya1, C0, C1, D0, D1);

        float pxb0 = fmaf(xa.z, Wt0, fmaf(xa.w, Wt1, bt0));
        float pxb1 = fmaf(xa.z, Wt2, fmaf(xa.w, Wt3, bt1));
        float pyb0 = fmaf(ya.z, Wt0, fmaf(ya.w, Wt1, bt0));
        float pyb1 = fmaf(ya.z, Wt2, fmaf(ya.w, Wt3, bt1));
        float dxB = xa.z - ya.z, dyB = xa.w - ya.w;
        float rB = exp2_fast(-NLOG2E * fmaf(dxB, dxB, dyB * dyB));
        float resB = rB * pair_val(tab4, pxb0, pxb1, pyb0, pyb1, C0, C1, D0, D1);

        out2[g] = make_float2(resA, resB);
    }
}

extern "C" void kernel_launch(void* const* d_in, const int* in_sizes, int n_in,
                              void* d_out, int out_size, void* d_ws, size_t ws_size,
                              hipStream_t stream) {
    const float* x  = (const float*)d_in[0];
    const float* y  = (const float*)d_in[1];
    const float* W0 = (const float*)d_in[2];
    const float* b0 = (const float*)d_in[3];
    const float* s0 = (const float*)d_in[4];
    const float* t0 = (const float*)d_in[5];
    const float* Ws = (const float*)d_in[6];
    const float* bs = (const float*)d_in[7];
    const float* ss = (const float*)d_in[8];
    const float* ts = (const float*)d_in[9];
    const float* Wf = (const float*)d_in[10];
    const float* bf = (const float*)d_in[11];
    float* out = (float*)d_out;
    float* fp  = (float*)d_ws;
    float* gt  = fp + 16;
    float4* gt4 = (float4*)(fp + 16 + TABSZ);   // (16+2304)*4 = 9280 B, 16B-aligned

    hipLaunchKernelGGL(setup_meta, dim3(1), dim3(64), 0, stream, W0, b0, s0, t0, fp);
    hipLaunchKernelGGL(build_table, dim3((TABSZ + 255) / 256), dim3(256), 0, stream,
                       Ws, bs, ss, ts, Wf, bf, fp, gt);
    hipLaunchKernelGGL(pack_table, dim3((TABSZ + 255) / 256), dim3(256), 0, stream,
                       gt, gt4);

    int n       = out_size;          // 8,388,608 pairs
    int ngroups = n / 2;             // float4-groups of 2 pairs
    int threads = ngroups / 4;       // 4 groups per thread = 8 pairs
    dim3 block(256);
    dim3 grid(threads / 256);
    hipLaunchKernelGGL(fraud_kernel, grid, block, 0, stream,
                       (const float4*)x, (const float4*)y, fp, gt4,
                       (float2*)out, threads);
}